// Round 1
// baseline (277.375 us; speedup 1.0000x reference)
//
#include <hip/hip_runtime.h>
#include <stdint.h>

#define NATOMS 4096
#define NCELLS 8000
#define KTOP 5
#define MNBR 8
#define NBRC 26

__device__ __forceinline__ unsigned long long umax64(unsigned long long a, unsigned long long b) {
    return a > b ? a : b;
}
__device__ __forceinline__ unsigned long long umin64(unsigned long long a, unsigned long long b) {
    return a < b ? a : b;
}

// cells[m] = (g[b], g[c], g[a]) with m = a*400 + b*20 + c, g[t] = t-10
// (derived from tf/jnp meshgrid 'xy' + transpose + reshape)
__device__ __forceinline__ void cell_coords_i(int m, int& x, int& y, int& z) {
    int a = m / 400;
    int r = m - a * 400;
    int b = r / 20;
    int c = r - b * 20;
    x = b - 10; y = c - 10; z = a - 10;
}

// ---------------------------------------------------------------------------
// Kernel A: nbr_cells = top_k(d_cc, 26) per cell. All squared distances are
// exact small integers; ties broken by LOWER cell index first (jax.lax.top_k
// stable semantics). Packed int key: dist*8192 + (8191 - j)  (unique).
// ---------------------------------------------------------------------------
__global__ __launch_bounds__(256) void knbrcells(int* __restrict__ nbrTable) {
    const int i = blockIdx.x;
    const int t = threadIdx.x;
    int xi, yi, zi;
    cell_coords_i(i, xi, yi, zi);

    int keys[32];
#pragma unroll
    for (int s = 0; s < 32; ++s) {
        int j = t + 256 * s;
        int key = -1;
        if (j < NCELLS) {
            int xj, yj, zj;
            cell_coords_i(j, xj, yj, zj);
            int dx = xi - xj, dy = yi - yj, dz = zi - zj;
            int dist = dx * dx + dy * dy + dz * dz;   // <= 1083
            key = dist * 8192 + (8191 - j);           // < 2^24, unique
        }
        keys[s] = key;
    }

    __shared__ int red[4];
    for (int r = 0; r < NBRC; ++r) {
        int best = -1;
#pragma unroll
        for (int s = 0; s < 32; ++s) best = max(best, keys[s]);
        for (int off = 32; off > 0; off >>= 1)
            best = max(best, __shfl_xor(best, off));
        if ((t & 63) == 0) red[t >> 6] = best;
        __syncthreads();
        int w = max(max(red[0], red[1]), max(red[2], red[3]));
        if (t == 0) nbrTable[i * NBRC + r] = 8191 - (w & 8191);
#pragma unroll
        for (int s = 0; s < 32; ++s) if (keys[s] == w) keys[s] = -1;
        __syncthreads();
    }
}

// ---------------------------------------------------------------------------
// Kernel B: atoms_in_cells = top_k(d_ca, 5) per cell (LARGEST sq-distances,
// faithful to source "bug"). d = (|cell|^2 + |atom|^2) - 2*dot, f32, no FMA.
// Key: (float_bits<<32) | (4095 - j): val desc, tie -> lower atom index.
// ---------------------------------------------------------------------------
__global__ __launch_bounds__(256) void katomsincells(const float* __restrict__ coords,
                                                     int* __restrict__ atomsInCells) {
    __shared__ float sc[NATOMS * 3];           // 48 KB staged coords
    const int i = blockIdx.x;
    const int t = threadIdx.x;

    {
        const float4* src = (const float4*)coords;
        float4* dst = (float4*)sc;
        for (int s = t; s < NATOMS * 3 / 4; s += 256) dst[s] = src[s];
    }
    __syncthreads();

    int xi_, yi_, zi_;
    cell_coords_i(i, xi_, yi_, zi_);
    const float cx = (float)xi_, cy = (float)yi_, cz = (float)zi_;
    const float scell = (float)(xi_ * xi_ + yi_ * yi_ + zi_ * zi_);  // exact int

    unsigned long long keys[16];
#pragma unroll
    for (int s = 0; s < 16; ++s) {
        int j = t + 256 * s;
        float ax = sc[j * 3], ay = sc[j * 3 + 1], az = sc[j * 3 + 2];
        float sa = __fadd_rn(__fadd_rn(__fmul_rn(ax, ax), __fmul_rn(ay, ay)), __fmul_rn(az, az));
        float dot = __fadd_rn(__fadd_rn(__fmul_rn(cx, ax), __fmul_rn(cy, ay)), __fmul_rn(cz, az));
        float val = __fsub_rn(__fadd_rn(scell, sa), __fmul_rn(2.0f, dot));
        keys[s] = ((unsigned long long)__float_as_uint(val) << 32) | (unsigned int)(4095 - j);
    }

    __shared__ unsigned long long redB[4];
    for (int r = 0; r < KTOP; ++r) {
        unsigned long long best = 0ull;
#pragma unroll
        for (int s = 0; s < 16; ++s) best = umax64(best, keys[s]);
        for (int off = 32; off > 0; off >>= 1)
            best = umax64(best, (unsigned long long)__shfl_xor((long long)best, off));
        if ((t & 63) == 0) redB[t >> 6] = best;
        __syncthreads();
        unsigned long long w = umax64(umax64(redB[0], redB[1]), umax64(redB[2], redB[3]));
        if (t == 0) atomsInCells[i * KTOP + r] = 4095 - (int)(w & 0xFFFFFFFFull);
#pragma unroll
        for (int s = 0; s < 16; ++s) if (keys[s] == w) keys[s] = 0ull;
        __syncthreads();
    }
}

// ---------------------------------------------------------------------------
// Kernel C: cells_for_atoms = argmin_j d_ac[i,j]. One wave per atom.
// d = (|atom|^2 + |cell|^2) - 2*dot. Key: (bits<<32)|m, min-reduce
// (val asc, tie -> lower cell index = argmin first-occurrence).
// ---------------------------------------------------------------------------
__global__ __launch_bounds__(256) void kcellsforatoms(const float* __restrict__ coords,
                                                      int* __restrict__ cellsForAtoms) {
    const int wid = threadIdx.x >> 6;
    const int lane = threadIdx.x & 63;
    const int atom = blockIdx.x * 4 + wid;

    float ax = coords[atom * 3], ay = coords[atom * 3 + 1], az = coords[atom * 3 + 2];
    float sa = __fadd_rn(__fadd_rn(__fmul_rn(ax, ax), __fmul_rn(ay, ay)), __fmul_rn(az, az));

    unsigned long long best = ~0ull;
    for (int s = 0; s < NCELLS / 64; ++s) {       // 125 iters
        int m = lane + 64 * s;
        int xi_, yi_, zi_;
        cell_coords_i(m, xi_, yi_, zi_);
        float cx = (float)xi_, cy = (float)yi_, cz = (float)zi_;
        float scell = (float)(xi_ * xi_ + yi_ * yi_ + zi_ * zi_);
        float dot = __fadd_rn(__fadd_rn(__fmul_rn(ax, cx), __fmul_rn(ay, cy)), __fmul_rn(az, cz));
        float val = __fsub_rn(__fadd_rn(sa, scell), __fmul_rn(2.0f, dot));
        unsigned long long key = ((unsigned long long)__float_as_uint(val) << 32) | (unsigned int)m;
        best = umin64(best, key);
    }
    for (int off = 32; off > 0; off >>= 1)
        best = umin64(best, (unsigned long long)__shfl_xor((long long)best, off));
    if (lane == 0) cellsForAtoms[atom] = (int)(best & 0xFFFFFFFFull);
}

// ---------------------------------------------------------------------------
// Kernel D: per atom — gather 130 candidates (26 nbr cells x 5 atoms, flat
// order p = cellSlot*5+atomSlot), top-8 LARGEST dists with tie -> lower p
// (duplicate candidates tie EXACTLY; position order is semantic), then energy.
// One wave per atom. Key: (dist_bits<<8) | (255-p).
// ---------------------------------------------------------------------------
__global__ __launch_bounds__(256) void kenergy(const float* __restrict__ coords,
                                               const float* __restrict__ vdw,
                                               const float* __restrict__ weights,
                                               const int* __restrict__ nbrTable,
                                               const int* __restrict__ atomsInCells,
                                               const int* __restrict__ cellsForAtoms,
                                               float* __restrict__ partials) {
    const int wid = threadIdx.x >> 6;
    const int lane = threadIdx.x & 63;
    const int i = blockIdx.x * 4 + wid;

    const float xi = coords[i * 3], yi = coords[i * 3 + 1], zi = coords[i * 3 + 2];
    const int ci = cellsForAtoms[i];

    int cand[3];
    unsigned long long keys[3];
#pragma unroll
    for (int s = 0; s < 3; ++s) {
        int p = lane + 64 * s;
        cand[s] = -1;
        keys[s] = 0ull;
        if (p < NBRC * KTOP) {
            int cellSlot = p / KTOP;
            int atomSlot = p - cellSlot * KTOP;
            int nc = nbrTable[ci * NBRC + cellSlot];
            int j = atomsInCells[nc * KTOP + atomSlot];
            cand[s] = j;
            float dx = __fsub_rn(xi, coords[j * 3]);
            float dy = __fsub_rn(yi, coords[j * 3 + 1]);
            float dz = __fsub_rn(zi, coords[j * 3 + 2]);
            float dist = __fadd_rn(__fadd_rn(__fmul_rn(dx, dx), __fmul_rn(dy, dy)), __fmul_rn(dz, dz));
            keys[s] = ((unsigned long long)__float_as_uint(dist) << 8) | (unsigned int)(255 - p);
        }
    }

    const float w0 = weights[0], w1 = weights[1], w2 = weights[2];
    const float w3 = weights[3], w4 = weights[4];
    const float vi = vdw[i];

    float esum = 0.0f;
    for (int r = 0; r < MNBR; ++r) {
        unsigned long long best = umax64(umax64(keys[0], keys[1]), keys[2]);
        for (int off = 32; off > 0; off >>= 1)
            best = umax64(best, (unsigned long long)__shfl_xor((long long)best, off));

        int p = 255 - (int)(best & 0xFFull);
        int slot = p >> 6;
        int owner = p & 63;
        int jsel = (slot == 0) ? cand[0] : (slot == 1) ? cand[1] : cand[2];
        int j = __shfl(jsel, owner);
        float dist = __uint_as_float((unsigned int)(best >> 8));

#pragma unroll
        for (int s = 0; s < 3; ++s) if (keys[s] == best) keys[s] = 0ull;

        // energy term (all lanes compute identically; lane 0's copy is used)
        float rr = __fsqrt_rn(__fadd_rn(dist, 1e-12f));
        float d = __fsub_rn(__fsub_rn(rr, vi), vdw[j]);
        float t1 = __fdiv_rn(d, 0.5f);
        float g1 = expf(-__fmul_rn(t1, t1));
        float t2 = __fdiv_rn(__fsub_rn(d, 3.0f), 2.0f);
        float g2 = expf(-__fmul_rn(t2, t2));
        float rep = (d < 0.0f) ? __fmul_rn(d, d) : 0.0f;
        float hyd = (d < 0.5f) ? 1.0f : ((d < 1.5f) ? __fsub_rn(1.5f, d) : 0.0f);
        float hb = (d < -0.7f) ? 1.0f : ((d < 0.0f) ? __fdiv_rn(-d, 0.7f) : 0.0f);
        float hval = __fadd_rn(__fadd_rn(__fadd_rn(__fadd_rn(
                         __fmul_rn(w0, g1), __fmul_rn(w1, g2)),
                         __fmul_rn(w2, rep)), __fmul_rn(w3, hyd)), __fmul_rn(w4, hb));
        float f = (d < 8.0f) ? hval : 0.0f;
        esum = __fadd_rn(esum, f);
    }
    if (lane == 0) partials[i] = esum;
}

// ---------------------------------------------------------------------------
// Kernel E: deterministic tree reduction of 4096 partials + final division.
// ---------------------------------------------------------------------------
__global__ __launch_bounds__(256) void kreduce(const float* __restrict__ partials,
                                               const float* __restrict__ weights,
                                               const float* __restrict__ nrot,
                                               float* __restrict__ out) {
    __shared__ float red[256];
    const int t = threadIdx.x;
    float s = 0.0f;
    for (int k = 0; k < NATOMS / 256; ++k) s = __fadd_rn(s, partials[t + 256 * k]);
    red[t] = s;
    __syncthreads();
    for (int off = 128; off > 0; off >>= 1) {
        if (t < off) red[t] = __fadd_rn(red[t], red[t + off]);
        __syncthreads();
    }
    if (t == 0) out[0] = __fdiv_rn(red[0], __fadd_rn(1.0f, __fmul_rn(weights[5], nrot[0])));
}

extern "C" void kernel_launch(void* const* d_in, const int* in_sizes, int n_in,
                              void* d_out, int out_size, void* d_ws, size_t ws_size,
                              hipStream_t stream) {
    const float* coords  = (const float*)d_in[0];
    const float* vdw     = (const float*)d_in[1];
    const float* weights = (const float*)d_in[2];
    const float* nrot    = (const float*)d_in[3];
    float* out = (float*)d_out;

    int* nbrTable      = (int*)d_ws;                      // 8000*26 ints
    int* atomsInCells  = nbrTable + NCELLS * NBRC;        // 8000*5 ints
    int* cellsForAtoms = atomsInCells + NCELLS * KTOP;    // 4096 ints
    float* partials    = (float*)(cellsForAtoms + NATOMS);// 4096 floats  (~1.0 MB total)

    knbrcells<<<NCELLS, 256, 0, stream>>>(nbrTable);
    katomsincells<<<NCELLS, 256, 0, stream>>>(coords, atomsInCells);
    kcellsforatoms<<<NATOMS / 4, 256, 0, stream>>>(coords, cellsForAtoms);
    kenergy<<<NATOMS / 4, 256, 0, stream>>>(coords, vdw, weights, nbrTable,
                                            atomsInCells, cellsForAtoms, partials);
    kreduce<<<1, 256, 0, stream>>>(partials, weights, nrot, out);
}

// Round 2
// 98.295 us; speedup vs baseline: 2.8219x; 2.8219x over previous
//
#include <hip/hip_runtime.h>
#include <stdint.h>

#define NATOMS 4096
#define NCELLS 8000
#define KTOP 5
#define MNBR 8
#define NBRC 26
#define MAXDIST 1083   // 3 * 19^2

__device__ __forceinline__ unsigned long long umax64(unsigned long long a, unsigned long long b) {
    return a > b ? a : b;
}
__device__ __forceinline__ unsigned long long umin64(unsigned long long a, unsigned long long b) {
    return a < b ? a : b;
}

// cells[m] = (g[b], g[c], g[a]) with m = a*400 + b*20 + c, g[t] = t-10
__device__ __forceinline__ void cell_coords_i(int m, int& x, int& y, int& z) {
    int a = m / 400;
    int r = m - a * 400;
    int b = r / 20;
    int c = r - b * 20;
    x = b - 10; y = c - 10; z = a - 10;
}

// ---------------------------------------------------------------------------
// kzero: clear flags + counters (graph-safe, deterministic)
// ---------------------------------------------------------------------------
__global__ void kzero(int* __restrict__ p, int n) {
    int i = blockIdx.x * 256 + threadIdx.x;
    if (i < n) p[i] = 0;
}

// ---------------------------------------------------------------------------
// Kernel C: cells_for_atoms = argmin over 8000 cells; also mark used cells.
// ---------------------------------------------------------------------------
__global__ __launch_bounds__(256) void kcellsforatoms(const float* __restrict__ coords,
                                                      int* __restrict__ cellsForAtoms,
                                                      int* __restrict__ usedFlag) {
    const int wid = threadIdx.x >> 6;
    const int lane = threadIdx.x & 63;
    const int atom = blockIdx.x * 4 + wid;

    float ax = coords[atom * 3], ay = coords[atom * 3 + 1], az = coords[atom * 3 + 2];
    float sa = __fadd_rn(__fadd_rn(__fmul_rn(ax, ax), __fmul_rn(ay, ay)), __fmul_rn(az, az));

    unsigned long long best = ~0ull;
    for (int s = 0; s < NCELLS / 64; ++s) {
        int m = lane + 64 * s;
        int xi_, yi_, zi_;
        cell_coords_i(m, xi_, yi_, zi_);
        float cx = (float)xi_, cy = (float)yi_, cz = (float)zi_;
        float scell = (float)(xi_ * xi_ + yi_ * yi_ + zi_ * zi_);
        float dot = __fadd_rn(__fadd_rn(__fmul_rn(ax, cx), __fmul_rn(ay, cy)), __fmul_rn(az, cz));
        float val = __fsub_rn(__fadd_rn(sa, scell), __fmul_rn(2.0f, dot));
        unsigned long long key = ((unsigned long long)__float_as_uint(val) << 32) | (unsigned int)m;
        best = umin64(best, key);
    }
    for (int off = 32; off > 0; off >>= 1)
        best = umin64(best, (unsigned long long)__shfl_xor((long long)best, off));
    if (lane == 0) {
        int c = (int)(best & 0xFFFFFFFFull);
        cellsForAtoms[atom] = c;
        usedFlag[c] = 1;   // benign write race (all write 1)
    }
}

// ---------------------------------------------------------------------------
// kcompact: flags -> list + count (order nondeterministic; contents are a set)
// ---------------------------------------------------------------------------
__global__ void kcompact(const int* __restrict__ flag, int* __restrict__ list,
                         int* __restrict__ cnt) {
    int c = blockIdx.x * 256 + threadIdx.x;
    if (c < NCELLS && flag[c]) {
        int p = atomicAdd(cnt, 1);
        list[p] = c;
    }
}

// ---------------------------------------------------------------------------
// Kernel A (new): top-26 LARGEST cell-cell sq-distances per USED cell via
// LDS counting histogram. Order: dist desc, index asc (jax.lax.top_k ties).
// Also marks the selected cells as "needed" for atoms_in_cells.
// ---------------------------------------------------------------------------
__global__ __launch_bounds__(256) void knbr2(const int* __restrict__ usedList,
                                             const int* __restrict__ usedCnt,
                                             int* __restrict__ nbrTable,
                                             int* __restrict__ neededFlag) {
    if (blockIdx.x >= *usedCnt) return;           // grid 4096 >= max used
    const int i = usedList[blockIdx.x];
    const int t = threadIdx.x;
    const int lane = t & 63, wv = t >> 6;

    int xi, yi, zi;
    cell_coords_i(i, xi, yi, zi);

    __shared__ uint32_t h[MAXDIST + 1];
    __shared__ int listGT[26];
    __shared__ int wsum[4];
    __shared__ int redm[4];
    __shared__ int sV, sN1, sClaim, cGT;

    for (int b = t; b <= MAXDIST; b += 256) h[b] = 0;
    __syncthreads();

    int dists[32];
#pragma unroll
    for (int s = 0; s < 32; ++s) {
        int j = t + 256 * s;
        int d = -1;
        if (j < NCELLS) {
            int xj, yj, zj;
            cell_coords_i(j, xj, yj, zj);
            int dx = xi - xj, dy = yi - yj, dz = zi - zj;
            d = dx * dx + dy * dy + dz * dz;
            atomicAdd(&h[d], 1u);
        }
        dists[s] = d;
    }
    __syncthreads();

    // find cutoff V and n1 = count(dist > V) < 26  (descending suffix scan)
    int base = MAXDIST - 5 * t;   // thread t covers bins [base-4, base]
    int cnt5 = 0;
#pragma unroll
    for (int k = 0; k < 5; ++k) {
        int b = base - k;
        if (b >= 0) cnt5 += (int)h[b];
    }
    int incl = cnt5;
    for (int off = 1; off < 64; off <<= 1) {
        int v = __shfl_up(incl, off);
        if (lane >= off) incl += v;
    }
    if (lane == 63) wsum[wv] = incl;
    __syncthreads();
    int add = 0;
    for (int k = 0; k < wv; ++k) add += wsum[k];
    incl += add;
    int P = incl - cnt5;
    if (P < 26 && P + cnt5 >= 26) {
        int run = P;
#pragma unroll
        for (int k = 0; k < 5; ++k) {
            int b = base - k;
            if (b < 0) break;
            int c = (int)h[b];
            if (run + c >= 26) { sV = b; sN1 = run; break; }
            run += c;
        }
    }
    if (t == 0) { cGT = 0; sClaim = -1; }
    __syncthreads();

    const int V = sV;
    const int n1 = sN1;

    // collect the (d > V) items; sort by (d desc, idx asc) via rank in 1 wave
#pragma unroll
    for (int s = 0; s < 32; ++s) {
        if (dists[s] > V) {
            int p = atomicAdd(&cGT, 1);
            listGT[p] = (dists[s] << 13) | (8191 - (t + 256 * s));
        }
    }
    __syncthreads();
    if (t < 64) {
        int key = (t < n1) ? listGT[t] : -1;
        int rank = 0;
        for (int m = 0; m < n1; ++m) rank += (listGT[m] > key) ? 1 : 0;
        if (t < n1) nbrTable[i * NBRC + rank] = 8191 - (key & 8191);
    }
    __syncthreads();

    // remaining slots: ties at V in ascending index
    for (int r = n1; r < NBRC; ++r) {
        int loc = 0x7FFFFFFF;
        int claimed = sClaim;
#pragma unroll
        for (int s = 0; s < 32; ++s) {
            int j = t + 256 * s;
            if (dists[s] == V && j > claimed) loc = min(loc, j);
        }
        for (int off = 32; off > 0; off >>= 1)
            loc = min(loc, __shfl_xor(loc, off));
        if (lane == 0) redm[wv] = loc;
        __syncthreads();
        int g = min(min(redm[0], redm[1]), min(redm[2], redm[3]));
        if (t == 0) { nbrTable[i * NBRC + r] = g; sClaim = g; }
        __syncthreads();
    }

    if (t < NBRC) neededFlag[nbrTable[i * NBRC + t]] = 1;
}

// ---------------------------------------------------------------------------
// Kernel B (new): atoms_in_cells = top-5 LARGEST atom distances, only for
// NEEDED cells. Grid-stride over needed list; coords staged once per block.
// ---------------------------------------------------------------------------
__global__ __launch_bounds__(256) void katoms2(const float* __restrict__ coords,
                                               const int* __restrict__ neededList,
                                               const int* __restrict__ neededCnt,
                                               int* __restrict__ atomsInCells) {
    const int nc = *neededCnt;
    if (blockIdx.x >= nc) return;
    __shared__ float sc[NATOMS * 3];
    __shared__ unsigned long long redB[4];
    const int t = threadIdx.x;
    const int lane = t & 63, wv = t >> 6;

    {
        const float4* src = (const float4*)coords;
        float4* dst = (float4*)sc;
        for (int s = t; s < NATOMS * 3 / 4; s += 256) dst[s] = src[s];
    }
    __syncthreads();

    for (int w = blockIdx.x; w < nc; w += gridDim.x) {
        const int i = neededList[w];
        int xi_, yi_, zi_;
        cell_coords_i(i, xi_, yi_, zi_);
        const float cx = (float)xi_, cy = (float)yi_, cz = (float)zi_;
        const float scell = (float)(xi_ * xi_ + yi_ * yi_ + zi_ * zi_);

        unsigned long long keys[16];
#pragma unroll
        for (int s = 0; s < 16; ++s) {
            int j = t + 256 * s;
            float ax = sc[j * 3], ay = sc[j * 3 + 1], az = sc[j * 3 + 2];
            float sa = __fadd_rn(__fadd_rn(__fmul_rn(ax, ax), __fmul_rn(ay, ay)), __fmul_rn(az, az));
            float dot = __fadd_rn(__fadd_rn(__fmul_rn(cx, ax), __fmul_rn(cy, ay)), __fmul_rn(cz, az));
            float val = __fsub_rn(__fadd_rn(scell, sa), __fmul_rn(2.0f, dot));
            keys[s] = ((unsigned long long)__float_as_uint(val) << 32) | (unsigned int)(4095 - j);
        }

        for (int r = 0; r < KTOP; ++r) {
            unsigned long long best = 0ull;
#pragma unroll
            for (int s = 0; s < 16; ++s) best = umax64(best, keys[s]);
            for (int off = 32; off > 0; off >>= 1)
                best = umax64(best, (unsigned long long)__shfl_xor((long long)best, off));
            if (lane == 0) redB[wv] = best;
            __syncthreads();
            unsigned long long wbest = umax64(umax64(redB[0], redB[1]), umax64(redB[2], redB[3]));
            if (t == 0) atomsInCells[i * KTOP + r] = 4095 - (int)(wbest & 0xFFFFFFFFull);
#pragma unroll
            for (int s = 0; s < 16; ++s) if (keys[s] == wbest) keys[s] = 0ull;
            __syncthreads();
        }
    }
}

// ---------------------------------------------------------------------------
// Kernel D: per-atom gather of 130 candidates, top-8 LARGEST (tie: lower flat
// position), then energy partial. One wave per atom.
// ---------------------------------------------------------------------------
__global__ __launch_bounds__(256) void kenergy(const float* __restrict__ coords,
                                               const float* __restrict__ vdw,
                                               const float* __restrict__ weights,
                                               const int* __restrict__ nbrTable,
                                               const int* __restrict__ atomsInCells,
                                               const int* __restrict__ cellsForAtoms,
                                               float* __restrict__ partials) {
    const int wid = threadIdx.x >> 6;
    const int lane = threadIdx.x & 63;
    const int i = blockIdx.x * 4 + wid;

    const float xi = coords[i * 3], yi = coords[i * 3 + 1], zi = coords[i * 3 + 2];
    const int ci = cellsForAtoms[i];

    int cand[3];
    unsigned long long keys[3];
#pragma unroll
    for (int s = 0; s < 3; ++s) {
        int p = lane + 64 * s;
        cand[s] = -1;
        keys[s] = 0ull;
        if (p < NBRC * KTOP) {
            int cellSlot = p / KTOP;
            int atomSlot = p - cellSlot * KTOP;
            int nc = nbrTable[ci * NBRC + cellSlot];
            int j = atomsInCells[nc * KTOP + atomSlot];
            cand[s] = j;
            float dx = __fsub_rn(xi, coords[j * 3]);
            float dy = __fsub_rn(yi, coords[j * 3 + 1]);
            float dz = __fsub_rn(zi, coords[j * 3 + 2]);
            float dist = __fadd_rn(__fadd_rn(__fmul_rn(dx, dx), __fmul_rn(dy, dy)), __fmul_rn(dz, dz));
            keys[s] = ((unsigned long long)__float_as_uint(dist) << 8) | (unsigned int)(255 - p);
        }
    }

    const float w0 = weights[0], w1 = weights[1], w2 = weights[2];
    const float w3 = weights[3], w4 = weights[4];
    const float vi = vdw[i];

    float esum = 0.0f;
    for (int r = 0; r < MNBR; ++r) {
        unsigned long long best = umax64(umax64(keys[0], keys[1]), keys[2]);
        for (int off = 32; off > 0; off >>= 1)
            best = umax64(best, (unsigned long long)__shfl_xor((long long)best, off));

        int p = 255 - (int)(best & 0xFFull);
        int slot = p >> 6;
        int owner = p & 63;
        int jsel = (slot == 0) ? cand[0] : (slot == 1) ? cand[1] : cand[2];
        int j = __shfl(jsel, owner);
        float dist = __uint_as_float((unsigned int)(best >> 8));

#pragma unroll
        for (int s = 0; s < 3; ++s) if (keys[s] == best) keys[s] = 0ull;

        float rr = __fsqrt_rn(__fadd_rn(dist, 1e-12f));
        float d = __fsub_rn(__fsub_rn(rr, vi), vdw[j]);
        float t1 = __fdiv_rn(d, 0.5f);
        float g1 = expf(-__fmul_rn(t1, t1));
        float t2 = __fdiv_rn(__fsub_rn(d, 3.0f), 2.0f);
        float g2 = expf(-__fmul_rn(t2, t2));
        float rep = (d < 0.0f) ? __fmul_rn(d, d) : 0.0f;
        float hyd = (d < 0.5f) ? 1.0f : ((d < 1.5f) ? __fsub_rn(1.5f, d) : 0.0f);
        float hb = (d < -0.7f) ? 1.0f : ((d < 0.0f) ? __fdiv_rn(-d, 0.7f) : 0.0f);
        float hval = __fadd_rn(__fadd_rn(__fadd_rn(__fadd_rn(
                         __fmul_rn(w0, g1), __fmul_rn(w1, g2)),
                         __fmul_rn(w2, rep)), __fmul_rn(w3, hyd)), __fmul_rn(w4, hb));
        float f = (d < 8.0f) ? hval : 0.0f;
        esum = __fadd_rn(esum, f);
    }
    if (lane == 0) partials[i] = esum;
}

// ---------------------------------------------------------------------------
// Kernel E: deterministic reduction + final division.
// ---------------------------------------------------------------------------
__global__ __launch_bounds__(256) void kreduce(const float* __restrict__ partials,
                                               const float* __restrict__ weights,
                                               const float* __restrict__ nrot,
                                               float* __restrict__ out) {
    __shared__ float red[256];
    const int t = threadIdx.x;
    float s = 0.0f;
    for (int k = 0; k < NATOMS / 256; ++k) s = __fadd_rn(s, partials[t + 256 * k]);
    red[t] = s;
    __syncthreads();
    for (int off = 128; off > 0; off >>= 1) {
        if (t < off) red[t] = __fadd_rn(red[t], red[t + off]);
        __syncthreads();
    }
    if (t == 0) out[0] = __fdiv_rn(red[0], __fadd_rn(1.0f, __fmul_rn(weights[5], nrot[0])));
}

extern "C" void kernel_launch(void* const* d_in, const int* in_sizes, int n_in,
                              void* d_out, int out_size, void* d_ws, size_t ws_size,
                              hipStream_t stream) {
    const float* coords  = (const float*)d_in[0];
    const float* vdw     = (const float*)d_in[1];
    const float* weights = (const float*)d_in[2];
    const float* nrot    = (const float*)d_in[3];
    float* out = (float*)d_out;

    int* nbrTable      = (int*)d_ws;                       // 208000
    int* atomsInCells  = nbrTable + NCELLS * NBRC;         // 40000
    int* cellsForAtoms = atomsInCells + NCELLS * KTOP;     // 4096
    float* partials    = (float*)(cellsForAtoms + NATOMS); // 4096
    int* usedFlag      = (int*)partials + NATOMS;          // 8000
    int* neededFlag    = usedFlag + NCELLS;                // 8000
    int* counters      = neededFlag + NCELLS;              // 2 (usedCnt, neededCnt)
    int* usedList      = counters + 2;                     // 4096
    int* neededList    = usedList + NATOMS;                // 8000
    // total ~1.13 MB

    kzero<<<63, 256, 0, stream>>>(usedFlag, 2 * NCELLS + 2);
    kcellsforatoms<<<NATOMS / 4, 256, 0, stream>>>(coords, cellsForAtoms, usedFlag);
    kcompact<<<32, 256, 0, stream>>>(usedFlag, usedList, &counters[0]);
    knbr2<<<NATOMS, 256, 0, stream>>>(usedList, &counters[0], nbrTable, neededFlag);
    kcompact<<<32, 256, 0, stream>>>(neededFlag, neededList, &counters[1]);
    katoms2<<<2048, 256, 0, stream>>>(coords, neededList, &counters[1], atomsInCells);
    kenergy<<<NATOMS / 4, 256, 0, stream>>>(coords, vdw, weights, nbrTable,
                                            atomsInCells, cellsForAtoms, partials);
    kreduce<<<1, 256, 0, stream>>>(partials, weights, nrot, out);
}

// Round 3
// 64.280 us; speedup vs baseline: 4.3151x; 1.5292x over previous
//
#include <hip/hip_runtime.h>
#include <stdint.h>

#define NATOMS 4096
#define NCELLS 8000
#define KTOP 5
#define MNBR 8
#define NBRC 26
#define HBINS 217   // window [Dmax-216, Dmax]

__device__ __forceinline__ unsigned long long umax64(unsigned long long a, unsigned long long b) {
    return a > b ? a : b;
}
__device__ __forceinline__ unsigned long long umin64(unsigned long long a, unsigned long long b) {
    return a < b ? a : b;
}

// cells[m] = (g[b], g[c], g[a]) with m = a*400 + b*20 + c, g[t] = t-10
__device__ __forceinline__ void cell_coords_i(int m, int& x, int& y, int& z) {
    int a = m / 400;
    int r = m - a * 400;
    int b = r / 20;
    int c = r - b * 20;
    x = b - 10; y = c - 10; z = a - 10;
}

// ---------------------------------------------------------------------------
// kzero: clear flags (graph-safe, deterministic)
// ---------------------------------------------------------------------------
__global__ void kzero(int* __restrict__ p, int n) {
    int i = blockIdx.x * 256 + threadIdx.x;
    if (i < n) p[i] = 0;
}

// ---------------------------------------------------------------------------
// Kernel C (analytic): argmin cell is inside the 4x4x4 neighborhood of
// floor(atom) (exact gap >= 1.0 in d^2 vs f32 err ~2e-4). Evaluate the SAME
// f32 expansion formula over 64 candidates (one per lane) with the same
// (bits<<32)|m min-key -> bitwise identical to the 8000-cell scan.
// ---------------------------------------------------------------------------
__global__ __launch_bounds__(256) void kcellsforatoms(const float* __restrict__ coords,
                                                      int* __restrict__ cellsForAtoms,
                                                      int* __restrict__ usedFlag) {
    const int wid = threadIdx.x >> 6;
    const int lane = threadIdx.x & 63;
    const int atom = blockIdx.x * 4 + wid;

    float ax = coords[atom * 3], ay = coords[atom * 3 + 1], az = coords[atom * 3 + 2];
    float sa = __fadd_rn(__fadd_rn(__fmul_rn(ax, ax), __fmul_rn(ay, ay)), __fmul_rn(az, az));

    int fx = (int)floorf(ax), fy = (int)floorf(ay), fz = (int)floorf(az);
    int vx = min(9, max(-10, fx - 1 + (lane & 3)));
    int vy = min(9, max(-10, fy - 1 + ((lane >> 2) & 3)));
    int vz = min(9, max(-10, fz - 1 + (lane >> 4)));
    int m = (vz + 10) * 400 + (vx + 10) * 20 + (vy + 10);

    float cx = (float)vx, cy = (float)vy, cz = (float)vz;
    float scell = (float)(vx * vx + vy * vy + vz * vz);
    float dot = __fadd_rn(__fadd_rn(__fmul_rn(ax, cx), __fmul_rn(ay, cy)), __fmul_rn(az, cz));
    float val = __fsub_rn(__fadd_rn(sa, scell), __fmul_rn(2.0f, dot));
    unsigned long long key = ((unsigned long long)__float_as_uint(val) << 32) | (unsigned int)m;

    for (int off = 32; off > 0; off >>= 1)
        key = umin64(key, (unsigned long long)__shfl_xor((long long)key, off));
    if (lane == 0) {
        int c = (int)(key & 0xFFFFFFFFull);
        cellsForAtoms[atom] = c;
        usedFlag[c] = 1;   // benign race (all write 1)
    }
}

// ---------------------------------------------------------------------------
// Kernel A: top-26 LARGEST cell-cell sq-dists per USED cell.
// Separable generation: thread t<400 owns (b,c); 20-step a-loop.
// Windowed LDS histogram [Dmax-216, Dmax] (26th-largest >= Dmax-216, proof:
// 27 cells from top-3 per-dim contribution values, per-dim drop <= 72).
// Tie semantics identical to the full-sort reference: dist desc, index asc.
// ---------------------------------------------------------------------------
__global__ __launch_bounds__(512) void knbr2(const int* __restrict__ usedFlag,
                                             int* __restrict__ nbrTable,
                                             int* __restrict__ neededFlag) {
    const int i = blockIdx.x;
    if (!usedFlag[i]) return;
    const int t = threadIdx.x;
    const int lane = t & 63, wv = t >> 6;

    int xi, yi, zi;
    cell_coords_i(i, xi, yi, zi);
    const int Mx = max((xi + 10) * (xi + 10), (9 - xi) * (9 - xi));
    const int My = max((yi + 10) * (yi + 10), (9 - yi) * (9 - yi));
    const int Mz = max((zi + 10) * (zi + 10), (9 - zi) * (9 - zi));
    const int lo = Mx + My + Mz - (HBINS - 1);

    __shared__ uint32_t h[HBINS];
    __shared__ int listGT[26];
    __shared__ int redm[8];
    __shared__ int sV, sN1, sClaim, cGT;

    for (int b = t; b < HBINS; b += 512) h[b] = 0;
    if (t == 0) { cGT = 0; sClaim = -1; }
    __syncthreads();

    int dists[20];
    int Dbc = 0;
    if (t < 400) {
        int b = t / 20, c = t - b * 20;
        int dxv = xi - (b - 10), dyv = yi - (c - 10);
        Dbc = dxv * dxv + dyv * dyv;
#pragma unroll
        for (int a = 0; a < 20; ++a) {
            int dzv = zi - (a - 10);
            int d = Dbc + dzv * dzv;
            dists[a] = d;
            if (d >= lo) atomicAdd(&h[d - lo], 1u);
        }
    }
    __syncthreads();

    // single-wave descending scan to find cutoff V and n1 = count(> V) < 26
    if (t < 64) {
        int cnt4 = 0;
#pragma unroll
        for (int k = 0; k < 4; ++k) {
            int b = (HBINS - 1) - (t * 4 + k);
            if (b >= 0) cnt4 += (int)h[b];
        }
        int incl = cnt4;
        for (int off = 1; off < 64; off <<= 1) {
            int v = __shfl_up(incl, off);
            if (lane >= off) incl += v;
        }
        int P = incl - cnt4;
        if (P < 26 && incl >= 26) {
            int run = P;
#pragma unroll
            for (int k = 0; k < 4; ++k) {
                int b = (HBINS - 1) - (t * 4 + k);
                int c = (b >= 0) ? (int)h[b] : 0;
                if (run + c >= 26) { sV = lo + b; sN1 = run; break; }
                run += c;
            }
        }
    }
    __syncthreads();

    const int V = sV;
    const int n1 = sN1;

    // collect (d > V) items, then rank-sort by (d desc, j asc) in one wave
    if (t < 400) {
#pragma unroll
        for (int a = 0; a < 20; ++a) {
            if (dists[a] > V) {
                int j = a * 400 + t;
                int p = atomicAdd(&cGT, 1);
                listGT[p] = (dists[a] << 13) | (8191 - j);
            }
        }
    }
    __syncthreads();
    if (t < 64) {
        int key = (t < n1) ? listGT[t] : -1;
        int rank = 0;
        for (int m = 0; m < n1; ++m) rank += (listGT[m] > key) ? 1 : 0;
        if (t < n1) nbrTable[i * NBRC + rank] = 8191 - (key & 8191);
    }
    __syncthreads();

    // remaining slots: ties at V in ascending index
    for (int r = n1; r < NBRC; ++r) {
        int loc = 0x7FFFFFFF;
        int claimed = sClaim;
        if (t < 400) {
#pragma unroll
            for (int a = 0; a < 20; ++a) {
                int j = a * 400 + t;
                if (dists[a] == V && j > claimed) loc = min(loc, j);
            }
        }
        for (int off = 32; off > 0; off >>= 1)
            loc = min(loc, __shfl_xor(loc, off));
        if (lane == 0) redm[wv] = loc;
        __syncthreads();
        if (t == 0) {
            int g = redm[0];
#pragma unroll
            for (int k = 1; k < 8; ++k) g = min(g, redm[k]);
            nbrTable[i * NBRC + r] = g;
            sClaim = g;
        }
        __syncthreads();
    }

    if (t < NBRC) neededFlag[nbrTable[i * NBRC + t]] = 1;
}

// ---------------------------------------------------------------------------
// Kernel B: atoms_in_cells = top-5 LARGEST atom distances, only for NEEDED
// cells. Direct global reads (single-pass data; L1/L2-hot), no LDS staging.
// ---------------------------------------------------------------------------
__global__ __launch_bounds__(256) void katoms2(const float* __restrict__ coords,
                                               const int* __restrict__ neededFlag,
                                               int* __restrict__ atomsInCells) {
    const int i = blockIdx.x;
    if (!neededFlag[i]) return;
    __shared__ unsigned long long redB[4];
    const int t = threadIdx.x;
    const int lane = t & 63, wv = t >> 6;

    int xi_, yi_, zi_;
    cell_coords_i(i, xi_, yi_, zi_);
    const float cx = (float)xi_, cy = (float)yi_, cz = (float)zi_;
    const float scell = (float)(xi_ * xi_ + yi_ * yi_ + zi_ * zi_);

    unsigned long long keys[16];
#pragma unroll
    for (int s = 0; s < 16; ++s) {
        int j = t + 256 * s;
        float ax = coords[j * 3], ay = coords[j * 3 + 1], az = coords[j * 3 + 2];
        float sa = __fadd_rn(__fadd_rn(__fmul_rn(ax, ax), __fmul_rn(ay, ay)), __fmul_rn(az, az));
        float dot = __fadd_rn(__fadd_rn(__fmul_rn(cx, ax), __fmul_rn(cy, ay)), __fmul_rn(cz, az));
        float val = __fsub_rn(__fadd_rn(scell, sa), __fmul_rn(2.0f, dot));
        keys[s] = ((unsigned long long)__float_as_uint(val) << 32) | (unsigned int)(4095 - j);
    }

    for (int r = 0; r < KTOP; ++r) {
        unsigned long long best = 0ull;
#pragma unroll
        for (int s = 0; s < 16; ++s) best = umax64(best, keys[s]);
        for (int off = 32; off > 0; off >>= 1)
            best = umax64(best, (unsigned long long)__shfl_xor((long long)best, off));
        if (lane == 0) redB[wv] = best;
        __syncthreads();
        unsigned long long wbest = umax64(umax64(redB[0], redB[1]), umax64(redB[2], redB[3]));
        if (t == 0) atomsInCells[i * KTOP + r] = 4095 - (int)(wbest & 0xFFFFFFFFull);
#pragma unroll
        for (int s = 0; s < 16; ++s) if (keys[s] == wbest) keys[s] = 0ull;
        __syncthreads();
    }
}

// ---------------------------------------------------------------------------
// Kernel D: per-atom gather of 130 candidates, top-8 LARGEST (tie: lower flat
// position), then energy partial. One wave per atom.
// ---------------------------------------------------------------------------
__global__ __launch_bounds__(256) void kenergy(const float* __restrict__ coords,
                                               const float* __restrict__ vdw,
                                               const float* __restrict__ weights,
                                               const int* __restrict__ nbrTable,
                                               const int* __restrict__ atomsInCells,
                                               const int* __restrict__ cellsForAtoms,
                                               float* __restrict__ partials) {
    const int wid = threadIdx.x >> 6;
    const int lane = threadIdx.x & 63;
    const int i = blockIdx.x * 4 + wid;

    const float xi = coords[i * 3], yi = coords[i * 3 + 1], zi = coords[i * 3 + 2];
    const int ci = cellsForAtoms[i];

    int cand[3];
    unsigned long long keys[3];
#pragma unroll
    for (int s = 0; s < 3; ++s) {
        int p = lane + 64 * s;
        cand[s] = -1;
        keys[s] = 0ull;
        if (p < NBRC * KTOP) {
            int cellSlot = p / KTOP;
            int atomSlot = p - cellSlot * KTOP;
            int nc = nbrTable[ci * NBRC + cellSlot];
            int j = atomsInCells[nc * KTOP + atomSlot];
            cand[s] = j;
            float dx = __fsub_rn(xi, coords[j * 3]);
            float dy = __fsub_rn(yi, coords[j * 3 + 1]);
            float dz = __fsub_rn(zi, coords[j * 3 + 2]);
            float dist = __fadd_rn(__fadd_rn(__fmul_rn(dx, dx), __fmul_rn(dy, dy)), __fmul_rn(dz, dz));
            keys[s] = ((unsigned long long)__float_as_uint(dist) << 8) | (unsigned int)(255 - p);
        }
    }

    const float w0 = weights[0], w1 = weights[1], w2 = weights[2];
    const float w3 = weights[3], w4 = weights[4];
    const float vi = vdw[i];

    float esum = 0.0f;
    for (int r = 0; r < MNBR; ++r) {
        unsigned long long best = umax64(umax64(keys[0], keys[1]), keys[2]);
        for (int off = 32; off > 0; off >>= 1)
            best = umax64(best, (unsigned long long)__shfl_xor((long long)best, off));

        int p = 255 - (int)(best & 0xFFull);
        int slot = p >> 6;
        int owner = p & 63;
        int jsel = (slot == 0) ? cand[0] : (slot == 1) ? cand[1] : cand[2];
        int j = __shfl(jsel, owner);
        float dist = __uint_as_float((unsigned int)(best >> 8));

#pragma unroll
        for (int s = 0; s < 3; ++s) if (keys[s] == best) keys[s] = 0ull;

        float rr = __fsqrt_rn(__fadd_rn(dist, 1e-12f));
        float d = __fsub_rn(__fsub_rn(rr, vi), vdw[j]);
        float t1 = __fdiv_rn(d, 0.5f);
        float g1 = expf(-__fmul_rn(t1, t1));
        float t2 = __fdiv_rn(__fsub_rn(d, 3.0f), 2.0f);
        float g2 = expf(-__fmul_rn(t2, t2));
        float rep = (d < 0.0f) ? __fmul_rn(d, d) : 0.0f;
        float hyd = (d < 0.5f) ? 1.0f : ((d < 1.5f) ? __fsub_rn(1.5f, d) : 0.0f);
        float hb = (d < -0.7f) ? 1.0f : ((d < 0.0f) ? __fdiv_rn(-d, 0.7f) : 0.0f);
        float hval = __fadd_rn(__fadd_rn(__fadd_rn(__fadd_rn(
                         __fmul_rn(w0, g1), __fmul_rn(w1, g2)),
                         __fmul_rn(w2, rep)), __fmul_rn(w3, hyd)), __fmul_rn(w4, hb));
        float f = (d < 8.0f) ? hval : 0.0f;
        esum = __fadd_rn(esum, f);
    }
    if (lane == 0) partials[i] = esum;
}

// ---------------------------------------------------------------------------
// Kernel E: deterministic reduction + final division.
// ---------------------------------------------------------------------------
__global__ __launch_bounds__(256) void kreduce(const float* __restrict__ partials,
                                               const float* __restrict__ weights,
                                               const float* __restrict__ nrot,
                                               float* __restrict__ out) {
    __shared__ float red[256];
    const int t = threadIdx.x;
    float s = 0.0f;
    for (int k = 0; k < NATOMS / 256; ++k) s = __fadd_rn(s, partials[t + 256 * k]);
    red[t] = s;
    __syncthreads();
    for (int off = 128; off > 0; off >>= 1) {
        if (t < off) red[t] = __fadd_rn(red[t], red[t + off]);
        __syncthreads();
    }
    if (t == 0) out[0] = __fdiv_rn(red[0], __fadd_rn(1.0f, __fmul_rn(weights[5], nrot[0])));
}

extern "C" void kernel_launch(void* const* d_in, const int* in_sizes, int n_in,
                              void* d_out, int out_size, void* d_ws, size_t ws_size,
                              hipStream_t stream) {
    const float* coords  = (const float*)d_in[0];
    const float* vdw     = (const float*)d_in[1];
    const float* weights = (const float*)d_in[2];
    const float* nrot    = (const float*)d_in[3];
    float* out = (float*)d_out;

    int* nbrTable      = (int*)d_ws;                       // 208000
    int* atomsInCells  = nbrTable + NCELLS * NBRC;         // 40000
    int* cellsForAtoms = atomsInCells + NCELLS * KTOP;     // 4096
    float* partials    = (float*)(cellsForAtoms + NATOMS); // 4096
    int* usedFlag      = (int*)partials + NATOMS;          // 8000
    int* neededFlag    = usedFlag + NCELLS;                // 8000

    kzero<<<63, 256, 0, stream>>>(usedFlag, 2 * NCELLS);
    kcellsforatoms<<<NATOMS / 4, 256, 0, stream>>>(coords, cellsForAtoms, usedFlag);
    knbr2<<<NCELLS, 512, 0, stream>>>(usedFlag, nbrTable, neededFlag);
    katoms2<<<NCELLS, 256, 0, stream>>>(coords, neededFlag, atomsInCells);
    kenergy<<<NATOMS / 4, 256, 0, stream>>>(coords, vdw, weights, nbrTable,
                                            atomsInCells, cellsForAtoms, partials);
    kreduce<<<1, 256, 0, stream>>>(partials, weights, nrot, out);
}